// Round 9
// baseline (309.582 us; speedup 1.0000x reference)
//
#include <hip/hip_runtime.h>
#include <hip/hip_bf16.h>

// (B, nf, D, H, W) = (4, 48, 12, 56, 56), fp32 in/out, bf16 MFMA internally.
// Sampled tensors are stored as SIX bf16 chunk-planes [6][NLOC][8ch]: each
// bilinear corner load is a 16B read at 16B pixel stride (~16 line-touches
// per wave-instruction). Round 9: taps split 4-WAY across the waves of a
// 256-thread block sharing 64 locations (round 8's 2-way split was still
// occupancy-limited at 25%); partial accumulators reduced via a 2-round LDS
// tree AFTER a full barrier (staging tiles are dead by then).
constexpr int B_ = 4, C_ = 48, D_ = 12, H_ = 56, W_ = 56;
constexpr int DHW_ = D_ * H_ * W_;        // 37632
constexpr int NLOC_ = B_ * DHW_;          // 150528 -> 2352 blocks of 256
constexpr int OFFC_ = 54;                 // 27 taps x 2 (dh, dw)
constexpr int NXCD_ = 8;

typedef short bf16x8 __attribute__((ext_vector_type(8)));
typedef float f32x4  __attribute__((ext_vector_type(4)));
typedef unsigned int u32x4 __attribute__((ext_vector_type(4)));
typedef unsigned int u32x2 __attribute__((ext_vector_type(2)));

__device__ __forceinline__ int xcd_swizzle(int bid, int nwg) {
    int xcd = bid % NXCD_, lid = bid / NXCD_;
    int q = nwg / NXCD_, r = nwg % NXCD_;
    return (xcd < r ? xcd * (q + 1) : r * (q + 1) + (xcd - r) * q) + lid;
}

__device__ __forceinline__ unsigned int f2bf_u(float f) {
    __hip_bfloat16 h = __float2bfloat16(f);
    return (unsigned int)__builtin_bit_cast(unsigned short, h);
}
__device__ __forceinline__ float bflo(unsigned int pv) {
    return __builtin_bit_cast(float, pv << 16);
}
__device__ __forceinline__ float bfhi(unsigned int pv) {
    return __builtin_bit_cast(float, pv & 0xffff0000u);
}

// 4-corner bilinear on a 16B chunk (8 bf16 channels), fp32 math, bf16 out.
__device__ __forceinline__ u32x4 interp4(u32x4 c00, u32x4 c01, u32x4 c10, u32x4 c11,
                                         f32x4 cw) {
    u32x4 pv;
#pragma unroll
    for (int u = 0; u < 4; ++u) {
        float lo = cw[0] * bflo(c00[u]);
        lo = fmaf(cw[1], bflo(c01[u]), lo);
        lo = fmaf(cw[2], bflo(c10[u]), lo);
        lo = fmaf(cw[3], bflo(c11[u]), lo);
        float hi = cw[0] * bfhi(c00[u]);
        hi = fmaf(cw[1], bfhi(c01[u]), hi);
        hi = fmaf(cw[2], bfhi(c10[u]), hi);
        hi = fmaf(cw[3], bfhi(c11[u]), hi);
        pv[u] = f2bf_u(lo) | (f2bf_u(hi) << 16);
    }
    return pv;
}

// Pack weights into MFMA A-fragment order (bf16):
// wf[k][mt][ks][lane][i] = W[oc=mt*16+(lane&15)][c=ks*32+8*(lane>>4)+i][tap k]
__global__ void __launch_bounds__(256) repack_frag_kernel(
    const float* __restrict__ w, unsigned short* __restrict__ wf, int OC, int MT) {
    int t = blockIdx.x * 256 + threadIdx.x;
    int total = 27 * MT * 1024;
    if (t >= total) return;
    int i    = t & 7;
    int lane = (t >> 3) & 63;
    int ks   = (t >> 9) & 1;
    int mt   = (t >> 10) % MT;
    int k    = t / (MT << 10);
    int oc = mt * 16 + (lane & 15);
    int c  = ks * 32 + 8 * (lane >> 4) + i;
    float v = (oc < OC && c < 48) ? w[((size_t)oc * 48 + c) * 27 + k] : 0.0f;
    wf[t] = (unsigned short)f2bf_u(v);
}

// fp32 [B][48][DHW] -> bf16 chunk-planes [6][NLOC][8].
__global__ void __launch_bounds__(256) to_cl_kernel(const float* __restrict__ x,
                                                    unsigned short* __restrict__ xcl) {
    int loc = blockIdx.x * 256 + threadIdx.x;
    int b = loc / DHW_, s = loc - b * DHW_;
    const float* xp = x + (size_t)b * (C_ * DHW_) + s;
#pragma unroll
    for (int q = 0; q < 6; ++q) {
        float v[8];
#pragma unroll
        for (int u = 0; u < 8; ++u) v[u] = xp[(size_t)(q * 8 + u) * DHW_];
        u32x4 o;
#pragma unroll
        for (int u = 0; u < 4; ++u)
            o[u] = f2bf_u(v[2 * u]) | (f2bf_u(v[2 * u + 1]) << 16);
        *(u32x4*)(xcl + ((size_t)q * NLOC_ + loc) * 8) = o;   // 16B/lane dense
    }
}

// ---------------- offset conv (plain 3x3x3, 54 outputs) via MFMA ----------------
// 4 waves share 64 locations; wave w does taps k === w (mod 4).
__global__ void __launch_bounds__(256) offconv_mfma(
    const unsigned short* __restrict__ xcl,   // [6][NLOC][8] bf16 chunk-planes
    const unsigned short* __restrict__ wf,    // frag-packed, MT=4
    const float* __restrict__ bo,             // [54]
    float* __restrict__ off) {                // [B][54][DHW] fp32
    __shared__ unsigned short S[4][64][64];   // 32 KB: staging, then exchange
    int tid = threadIdx.x, wid = tid >> 6, lane = tid & 63;
    int base = xcd_swizzle(blockIdx.x, gridDim.x) * 64;
    int loc = base + lane;
    int b = loc / DHW_;
    int sp = loc - b * DHW_;
    int w = sp % W_; int t1 = sp / W_;
    int h = t1 % H_; int d = t1 / H_;
    int g = lane >> 4, li = lane & 15, l7 = lane & 7;

    u32x4 z = {0, 0, 0, 0};
    *(u32x4*)&S[wid][lane][(6 ^ l7) * 8] = z;   // K-pad channels 48..63
    *(u32x4*)&S[wid][lane][(7 ^ l7) * 8] = z;

    f32x4 acc[4][4];
#pragma unroll
    for (int mt = 0; mt < 4; ++mt)
#pragma unroll
        for (int nt = 0; nt < 4; ++nt) acc[mt][nt] = (f32x4){0.f, 0.f, 0.f, 0.f};

    const u32x4* plane[6];
#pragma unroll
    for (int q = 0; q < 6; ++q)
        plane[q] = (const u32x4*)(xcl + ((size_t)q * NLOC_ + (size_t)b * DHW_) * 8);

#pragma unroll 1
    for (int i = 0; i < 7; ++i) {
        int k = wid + 4 * i;
        if (k >= 27) break;                    // wave-uniform
        int kd = k / 9 - 1, kh = (k / 3) % 3 - 1, kw = k % 3 - 1;
        int pd = d + kd, ph = h + kh, pw = w + kw;
        bool valid = (pd >= 0) & (pd < D_) & (ph >= 0) & (ph < H_) & (pw >= 0) & (pw < W_);
        int pdc = min(max(pd, 0), D_ - 1);
        int phc = min(max(ph, 0), H_ - 1);
        int pwc = min(max(pw, 0), W_ - 1);
        int pix = (pdc * H_ + phc) * W_ + pwc;
        u32x4 pv[6];
#pragma unroll
        for (int cc = 0; cc < 6; ++cc) pv[cc] = plane[cc][pix];   // coalesced 16B
#pragma unroll
        for (int cc = 0; cc < 6; ++cc) {
            if (!valid) pv[cc] = z;
            *(u32x4*)&S[wid][lane][(cc ^ l7) * 8] = pv[cc];
        }
        const unsigned short* wk = wf + (size_t)k * 4096 + lane * 8;
        bf16x8 a[4][2];
#pragma unroll
        for (int mt = 0; mt < 4; ++mt)
#pragma unroll
            for (int ks = 0; ks < 2; ++ks)
                a[mt][ks] = *(const bf16x8*)&wk[(mt * 2 + ks) * 512];
#pragma unroll
        for (int nt = 0; nt < 4; ++nt) {
            const unsigned short* sr = &S[wid][nt * 16 + li][0];
            bf16x8 b0 = *(const bf16x8*)&sr[((0 + g) ^ l7) * 8];
            bf16x8 b1 = *(const bf16x8*)&sr[((4 + g) ^ l7) * 8];
#pragma unroll
            for (int mt = 0; mt < 4; ++mt) {
                acc[mt][nt] = __builtin_amdgcn_mfma_f32_16x16x32_bf16(a[mt][0], b0, acc[mt][nt], 0, 0, 0);
                acc[mt][nt] = __builtin_amdgcn_mfma_f32_16x16x32_bf16(a[mt][1], b1, acc[mt][nt], 0, 0, 0);
            }
        }
    }

    // 2-round LDS reduction tree. acc = 64 f32/lane = 16KB/wave region.
    // Barrier FIRST: staging tiles (aliased by XCH) must be dead (round-7 bug).
    float* XCH = (float*)&S[0][0][0];          // region r at r*4096 floats
    __syncthreads();
    if (wid == 1 || wid == 3) {
        float* dst = XCH + (wid >> 1) * 4096;
#pragma unroll
        for (int mt = 0; mt < 4; ++mt)
#pragma unroll
            for (int nt = 0; nt < 4; ++nt)
                *(f32x4*)(dst + (mt * 4 + nt) * 256 + lane * 4) = acc[mt][nt];
    }
    __syncthreads();
    if (wid == 0 || wid == 2) {
        float* src = XCH + (wid >> 1) * 4096;
#pragma unroll
        for (int mt = 0; mt < 4; ++mt)
#pragma unroll
            for (int nt = 0; nt < 4; ++nt)
                acc[mt][nt] += *(f32x4*)(src + (mt * 4 + nt) * 256 + lane * 4);
    }
    __syncthreads();
    if (wid == 2) {
#pragma unroll
        for (int mt = 0; mt < 4; ++mt)
#pragma unroll
            for (int nt = 0; nt < 4; ++nt)
                *(f32x4*)(XCH + (mt * 4 + nt) * 256 + lane * 4) = acc[mt][nt];
    }
    __syncthreads();
    if (wid != 0) return;
#pragma unroll
    for (int mt = 0; mt < 4; ++mt)
#pragma unroll
        for (int nt = 0; nt < 4; ++nt)
            acc[mt][nt] += *(f32x4*)(XCH + (mt * 4 + nt) * 256 + lane * 4);

    int s0 = base - b * DHW_;
#pragma unroll
    for (int mt = 0; mt < 4; ++mt) {
#pragma unroll
        for (int r = 0; r < 4; ++r) {
            int oc = mt * 16 + 4 * g + r;
            if (oc < OFFC_) {
                float bb = bo[oc];
#pragma unroll
                for (int nt = 0; nt < 4; ++nt) {
                    size_t addr = ((size_t)b * OFFC_ + oc) * DHW_ + (s0 + nt * 16 + li);
                    off[addr] = acc[mt][nt][r] + bb;
                }
            }
        }
    }
}

// ---------------- deformable conv (bilinear HW, integer D) via MFMA ----------------
template <int LEAKY, int RESID, int CLOUT>
__global__ void __launch_bounds__(256) deform_mfma(
    const unsigned short* __restrict__ scl,   // [6][NLOC][8] bf16 chunk-planes
    const float* __restrict__ off,            // [B][54][DHW] fp32
    const unsigned short* __restrict__ wf,    // frag-packed, MT=3
    const float* __restrict__ bias,           // [48]
    const float* __restrict__ resid,          // [B][48][DHW] fp32 (RESID)
    float* __restrict__ dstf,                 // [B][48][DHW] fp32 (!CLOUT)
    unsigned short* __restrict__ dstcl) {     // [6][NLOC][8] bf16 (CLOUT)
    __shared__ unsigned short S[4][64][64];   // 32 KB: staging, then exchange
    int tid = threadIdx.x, wid = tid >> 6, lane = tid & 63;
    int base = xcd_swizzle(blockIdx.x, gridDim.x) * 64;
    int loc = base + lane;
    int b = loc / DHW_;
    int sp = loc - b * DHW_;
    int w = sp % W_; int t1 = sp / W_;
    int h = t1 % H_; int d = t1 / H_;
    int g = lane >> 4, li = lane & 15, l7 = lane & 7;

    u32x4 z = {0, 0, 0, 0};
    *(u32x4*)&S[wid][lane][(6 ^ l7) * 8] = z;
    *(u32x4*)&S[wid][lane][(7 ^ l7) * 8] = z;

    f32x4 acc[3][4];
#pragma unroll
    for (int mt = 0; mt < 3; ++mt)
#pragma unroll
        for (int nt = 0; nt < 4; ++nt) acc[mt][nt] = (f32x4){0.f, 0.f, 0.f, 0.f};

    const u32x4* plane[6];
#pragma unroll
    for (int q = 0; q < 6; ++q)
        plane[q] = (const u32x4*)(scl + ((size_t)q * NLOC_ + (size_t)b * DHW_) * 8);
    const float* ob = off + (size_t)b * (OFFC_ * DHW_) + sp;

#pragma unroll 1
    for (int i = 0; i < 7; ++i) {
        int k = wid + 4 * i;
        if (k >= 27) break;                    // wave-uniform
        int kd = k / 9 - 1, kh = (k / 3) % 3 - 1, kw = k % 3 - 1;
        int pd = d + kd;
        bool vd = (pd >= 0) & (pd < D_);
        int pdc = min(max(pd, 0), D_ - 1);

        float odh = ob[(size_t)(2 * k + 0) * DHW_];
        float odw = ob[(size_t)(2 * k + 1) * DHW_];
        float phf = (float)(h + kh) + odh;
        float pwf = (float)(w + kw) + odw;
        float h0f = floorf(phf), w0f = floorf(pwf);
        float th = phf - h0f, tw = pwf - w0f;
        int h0 = (int)h0f, w0 = (int)w0f;

        int pix[4];
        f32x4 cw;
#pragma unroll
        for (int dh = 0; dh < 2; ++dh) {
            int hh = h0 + dh;
            bool vh = vd & (hh >= 0) & (hh < H_);
            int hhc = min(max(hh, 0), H_ - 1);
            float wh = dh ? th : 1.0f - th;
#pragma unroll
            for (int dw = 0; dw < 2; ++dw) {
                int ww = w0 + dw;
                bool v = vh & (ww >= 0) & (ww < W_);
                int wwc = min(max(ww, 0), W_ - 1);
                float wwt = dw ? tw : 1.0f - tw;
                pix[dh * 2 + dw] = (pdc * H_ + hhc) * W_ + wwc;   // clamped in-bounds
                cw[dh * 2 + dw] = v ? wh * wwt : 0.0f;
            }
        }

        // two halves of 12 staged 16B gathers (3 chunk-planes x 4 corners)
#pragma unroll
        for (int half = 0; half < 2; ++half) {
            u32x4 st[3][4];
#pragma unroll
            for (int cc = 0; cc < 3; ++cc)
#pragma unroll
                for (int j = 0; j < 4; ++j)
                    st[cc][j] = plane[half * 3 + cc][pix[j]];
#pragma unroll
            for (int cc = 0; cc < 3; ++cc) {
                u32x4 pv = interp4(st[cc][0], st[cc][1], st[cc][2], st[cc][3], cw);
                *(u32x4*)&S[wid][lane][((half * 3 + cc) ^ l7) * 8] = pv;
            }
        }

        const unsigned short* wk = wf + (size_t)k * 3072 + lane * 8;
        bf16x8 a[3][2];
#pragma unroll
        for (int mt = 0; mt < 3; ++mt)
#pragma unroll
            for (int ks = 0; ks < 2; ++ks)
                a[mt][ks] = *(const bf16x8*)&wk[(mt * 2 + ks) * 512];
#pragma unroll
        for (int nt = 0; nt < 4; ++nt) {
            const unsigned short* sr = &S[wid][nt * 16 + li][0];
            bf16x8 b0 = *(const bf16x8*)&sr[((0 + g) ^ l7) * 8];
            bf16x8 b1 = *(const bf16x8*)&sr[((4 + g) ^ l7) * 8];
#pragma unroll
            for (int mt = 0; mt < 3; ++mt) {
                acc[mt][nt] = __builtin_amdgcn_mfma_f32_16x16x32_bf16(a[mt][0], b0, acc[mt][nt], 0, 0, 0);
                acc[mt][nt] = __builtin_amdgcn_mfma_f32_16x16x32_bf16(a[mt][1], b1, acc[mt][nt], 0, 0, 0);
            }
        }
    }

    // 2-round LDS reduction tree. acc = 48 f32/lane = 12KB/wave region.
    // Barrier FIRST: staging tiles (aliased by XCH) must be dead (round-7 bug).
    float* XCH = (float*)&S[0][0][0];          // region r at r*3072 floats
    __syncthreads();
    if (wid == 1 || wid == 3) {
        float* dst = XCH + (wid >> 1) * 3072;
#pragma unroll
        for (int mt = 0; mt < 3; ++mt)
#pragma unroll
            for (int nt = 0; nt < 4; ++nt)
                *(f32x4*)(dst + (mt * 4 + nt) * 256 + lane * 4) = acc[mt][nt];
    }
    __syncthreads();
    if (wid == 0 || wid == 2) {
        float* src = XCH + (wid >> 1) * 3072;
#pragma unroll
        for (int mt = 0; mt < 3; ++mt)
#pragma unroll
            for (int nt = 0; nt < 4; ++nt)
                acc[mt][nt] += *(f32x4*)(src + (mt * 4 + nt) * 256 + lane * 4);
    }
    __syncthreads();
    if (wid == 2) {
#pragma unroll
        for (int mt = 0; mt < 3; ++mt)
#pragma unroll
            for (int nt = 0; nt < 4; ++nt)
                *(f32x4*)(XCH + (mt * 4 + nt) * 256 + lane * 4) = acc[mt][nt];
    }
    __syncthreads();
    if (wid != 0) return;
#pragma unroll
    for (int mt = 0; mt < 3; ++mt)
#pragma unroll
        for (int nt = 0; nt < 4; ++nt)
            acc[mt][nt] += *(f32x4*)(XCH + (mt * 4 + nt) * 256 + lane * 4);

    if (CLOUT) {
        // Transpose D-tile through (now free) LDS, then write bf16 chunk-planes
        // (16B/lane dense per plane, fully coalesced). Only wave 0 is alive.
        unsigned short* Sb = &S[0][0][0];   // row stride 64 u16 = 128 B
#pragma unroll
        for (int mt = 0; mt < 3; ++mt) {
#pragma unroll
            for (int nt = 0; nt < 4; ++nt) {
                float v[4];
#pragma unroll
                for (int r = 0; r < 4; ++r) {
                    int oc = mt * 16 + 4 * g + r;
                    float t = acc[mt][nt][r] + bias[oc];
                    if (LEAKY) t = (t >= 0.f) ? t : 0.1f * t;
                    v[r] = t;
                }
                int row = nt * 16 + li;
                int colb = (mt * 32 + 8 * g) ^ ((li & 7) << 4);
                u32x2 pp = {f2bf_u(v[0]) | (f2bf_u(v[1]) << 16),
                            f2bf_u(v[2]) | (f2bf_u(v[3]) << 16)};
                *(u32x2*)((char*)(Sb + (size_t)row * 64) + colb) = pp;
            }
        }
        unsigned short* myrow = Sb + (size_t)lane * 64;
#pragma unroll
        for (int s = 0; s < 6; ++s) {
            u32x4 c = *(u32x4*)((char*)myrow + ((s * 16) ^ ((lane & 7) << 4)));
            *(u32x4*)(dstcl + ((size_t)s * NLOC_ + loc) * 8) = c;
        }
    } else {
        int s0 = base - b * DHW_;
#pragma unroll
        for (int mt = 0; mt < 3; ++mt) {
#pragma unroll
            for (int r = 0; r < 4; ++r) {
                int oc = mt * 16 + 4 * g + r;
                float bb = bias[oc];
#pragma unroll
                for (int nt = 0; nt < 4; ++nt) {
                    size_t addr = ((size_t)b * C_ + oc) * DHW_ + (s0 + nt * 16 + li);
                    float v = acc[mt][nt][r] + bb;
                    if (LEAKY) v = (v >= 0.0f) ? v : 0.1f * v;
                    if (RESID) v += resid[addr];
                    dstf[addr] = v;
                }
            }
        }
    }
}

extern "C" void kernel_launch(void* const* d_in, const int* in_sizes, int n_in,
                              void* d_out, int out_size, void* d_ws, size_t ws_size,
                              hipStream_t stream) {
    const float* x      = (const float*)d_in[0];
    const float* w_off0 = (const float*)d_in[1];
    const float* b_off0 = (const float*)d_in[2];
    const float* w0     = (const float*)d_in[3];
    const float* b0     = (const float*)d_in[4];
    const float* w_off1 = (const float*)d_in[5];
    const float* b_off1 = (const float*)d_in[6];
    const float* w1     = (const float*)d_in[7];
    const float* b1     = (const float*)d_in[8];
    float* out = (float*)d_out;

    // ws: off (54*NLOC f32) | xcl (48*NLOC bf16) | hcl (48*NLOC bf16) | wf_off | wf_conv
    float* off_buf = (float*)d_ws;
    unsigned short* xcl = (unsigned short*)(off_buf + (size_t)OFFC_ * NLOC_);
    unsigned short* hcl = xcl + (size_t)NLOC_ * 48;
    unsigned short* wf_off  = hcl + (size_t)NLOC_ * 48;
    unsigned short* wf_conv = wf_off + 27 * 4 * 1024;

    dim3 blk(256);
    int nblk = NLOC_ / 64;    // 2352 (divisible by 8)

    to_cl_kernel<<<NLOC_ / 256, blk, 0, stream>>>(x, xcl);

    // --- layer 0 ---
    repack_frag_kernel<<<(27 * 4 * 1024 + 255) / 256, blk, 0, stream>>>(w_off0, wf_off, OFFC_, 4);
    repack_frag_kernel<<<(27 * 3 * 1024 + 255) / 256, blk, 0, stream>>>(w0, wf_conv, C_, 3);
    offconv_mfma<<<nblk, blk, 0, stream>>>(xcl, wf_off, b_off0, off_buf);
    deform_mfma<1, 0, 1><<<nblk, blk, 0, stream>>>(xcl, off_buf, wf_conv, b0, nullptr, nullptr, hcl);

    // --- layer 1 ---
    repack_frag_kernel<<<(27 * 4 * 1024 + 255) / 256, blk, 0, stream>>>(w_off1, wf_off, OFFC_, 4);
    repack_frag_kernel<<<(27 * 3 * 1024 + 255) / 256, blk, 0, stream>>>(w1, wf_conv, C_, 3);
    offconv_mfma<<<nblk, blk, 0, stream>>>(hcl, wf_off, b_off1, off_buf);
    deform_mfma<0, 1, 0><<<nblk, blk, 0, stream>>>(hcl, off_buf, wf_conv, b1, x, out, nullptr);
}

// Round 10
// 300.498 us; speedup vs baseline: 1.0302x; 1.0302x over previous
//
#include <hip/hip_runtime.h>
#include <hip/hip_bf16.h>

// (B, nf, D, H, W) = (4, 48, 12, 56, 56), fp32 in/out, bf16 MFMA internally.
// Sampled tensors are stored as SIX bf16 chunk-planes [6][NLOC][8ch]: each
// bilinear corner load is a 16B read at 16B pixel stride (~16 line-touches
// per wave-instruction). Round 10: round-8 structure (2-way tap split across
// a 128-thread wave pair, 16KB LDS) + PACKED-f32 interpolation: v_pk_fma_f32
// halves the FMA instruction count and v_cvt_pk_bf16_f32 packs results in
// one op (interp was the measured VALU bound: 53% busy, ~450 VALU ops/tap).
constexpr int B_ = 4, C_ = 48, D_ = 12, H_ = 56, W_ = 56;
constexpr int DHW_ = D_ * H_ * W_;        // 37632
constexpr int NLOC_ = B_ * DHW_;          // 150528 -> 2352 blocks of 128
constexpr int OFFC_ = 54;                 // 27 taps x 2 (dh, dw)
constexpr int NXCD_ = 8;

typedef short bf16x8 __attribute__((ext_vector_type(8)));
typedef float f32x4  __attribute__((ext_vector_type(4)));
typedef float f32x2  __attribute__((ext_vector_type(2)));
typedef unsigned int u32x4 __attribute__((ext_vector_type(4)));
typedef unsigned int u32x2 __attribute__((ext_vector_type(2)));

__device__ __forceinline__ int xcd_swizzle(int bid, int nwg) {
    int xcd = bid % NXCD_, lid = bid / NXCD_;
    int q = nwg / NXCD_, r = nwg % NXCD_;
    return (xcd < r ? xcd * (q + 1) : r * (q + 1) + (xcd - r) * q) + lid;
}

__device__ __forceinline__ unsigned int f2bf_u(float f) {
    __hip_bfloat16 h = __float2bfloat16(f);
    return (unsigned int)__builtin_bit_cast(unsigned short, h);
}

// unpack a u32 holding 2 bf16 (even ch in [15:0], odd ch in [31:16]) -> f32 pair
__device__ __forceinline__ f32x2 bfpair(unsigned int pv) {
    f32x2 r;
    r.x = __builtin_bit_cast(float, pv << 16);
    r.y = __builtin_bit_cast(float, pv & 0xffff0000u);
    return r;
}
__device__ __forceinline__ f32x2 pk_mul(f32x2 a, f32x2 b) {
    f32x2 d;
    asm("v_pk_mul_f32 %0, %1, %2" : "=v"(d) : "v"(a), "v"(b));
    return d;
}
__device__ __forceinline__ f32x2 pk_fma(f32x2 a, f32x2 b, f32x2 c) {
    f32x2 d;
    asm("v_pk_fma_f32 %0, %1, %2, %3" : "=v"(d) : "v"(a), "v"(b), "v"(c));
    return d;
}
// pack {lo,hi} f32 pair -> u32 of 2 bf16 (RNE), single instruction
__device__ __forceinline__ unsigned int cvt_pk_bf16(float lo, float hi) {
    unsigned int r;
    asm("v_cvt_pk_bf16_f32 %0, %1, %2" : "=v"(r) : "v"(lo), "v"(hi));
    return r;
}

// 4-corner bilinear on a 16B chunk (8 bf16 channels), packed-f32 math.
__device__ __forceinline__ u32x4 interp4_pk(u32x4 c00, u32x4 c01, u32x4 c10, u32x4 c11,
                                            f32x2 w0, f32x2 w1, f32x2 w2, f32x2 w3) {
    u32x4 pv;
#pragma unroll
    for (int u = 0; u < 4; ++u) {
        f32x2 r = pk_mul(w0, bfpair(c00[u]));
        r = pk_fma(w1, bfpair(c01[u]), r);
        r = pk_fma(w2, bfpair(c10[u]), r);
        r = pk_fma(w3, bfpair(c11[u]), r);
        pv[u] = cvt_pk_bf16(r.x, r.y);
    }
    return pv;
}

// Pack weights into MFMA A-fragment order (bf16):
// wf[k][mt][ks][lane][i] = W[oc=mt*16+(lane&15)][c=ks*32+8*(lane>>4)+i][tap k]
__global__ void __launch_bounds__(256) repack_frag_kernel(
    const float* __restrict__ w, unsigned short* __restrict__ wf, int OC, int MT) {
    int t = blockIdx.x * 256 + threadIdx.x;
    int total = 27 * MT * 1024;
    if (t >= total) return;
    int i    = t & 7;
    int lane = (t >> 3) & 63;
    int ks   = (t >> 9) & 1;
    int mt   = (t >> 10) % MT;
    int k    = t / (MT << 10);
    int oc = mt * 16 + (lane & 15);
    int c  = ks * 32 + 8 * (lane >> 4) + i;
    float v = (oc < OC && c < 48) ? w[((size_t)oc * 48 + c) * 27 + k] : 0.0f;
    wf[t] = (unsigned short)f2bf_u(v);
}

// fp32 [B][48][DHW] -> bf16 chunk-planes [6][NLOC][8].
__global__ void __launch_bounds__(256) to_cl_kernel(const float* __restrict__ x,
                                                    unsigned short* __restrict__ xcl) {
    int loc = blockIdx.x * 256 + threadIdx.x;
    int b = loc / DHW_, s = loc - b * DHW_;
    const float* xp = x + (size_t)b * (C_ * DHW_) + s;
#pragma unroll
    for (int q = 0; q < 6; ++q) {
        float v[8];
#pragma unroll
        for (int u = 0; u < 8; ++u) v[u] = xp[(size_t)(q * 8 + u) * DHW_];
        u32x4 o;
#pragma unroll
        for (int u = 0; u < 4; ++u)
            o[u] = cvt_pk_bf16(v[2 * u], v[2 * u + 1]);
        *(u32x4*)(xcl + ((size_t)q * NLOC_ + loc) * 8) = o;   // 16B/lane dense
    }
}

// ---------------- offset conv (plain 3x3x3, 54 outputs) via MFMA ----------------
// 2 waves share 64 locations; wave w does taps k === w (mod 2).
__global__ void __launch_bounds__(128) offconv_mfma(
    const unsigned short* __restrict__ xcl,   // [6][NLOC][8] bf16 chunk-planes
    const unsigned short* __restrict__ wf,    // frag-packed, MT=4
    const float* __restrict__ bo,             // [54]
    float* __restrict__ off) {                // [B][54][DHW] fp32
    __shared__ unsigned short S[2][64][64];
    int tid = threadIdx.x, wid = tid >> 6, lane = tid & 63;
    int base = xcd_swizzle(blockIdx.x, gridDim.x) * 64;
    int loc = base + lane;
    int b = loc / DHW_;
    int sp = loc - b * DHW_;
    int w = sp % W_; int t1 = sp / W_;
    int h = t1 % H_; int d = t1 / H_;
    int g = lane >> 4, li = lane & 15, l7 = lane & 7;

    u32x4 z = {0, 0, 0, 0};
    *(u32x4*)&S[wid][lane][(6 ^ l7) * 8] = z;   // K-pad channels 48..63
    *(u32x4*)&S[wid][lane][(7 ^ l7) * 8] = z;

    f32x4 acc[4][4];
#pragma unroll
    for (int mt = 0; mt < 4; ++mt)
#pragma unroll
        for (int nt = 0; nt < 4; ++nt) acc[mt][nt] = (f32x4){0.f, 0.f, 0.f, 0.f};

    const u32x4* plane[6];
#pragma unroll
    for (int q = 0; q < 6; ++q)
        plane[q] = (const u32x4*)(xcl + ((size_t)q * NLOC_ + (size_t)b * DHW_) * 8);

#pragma unroll 1
    for (int i = 0; i < 14; ++i) {
        int k = wid + 2 * i;
        if (k >= 27) break;
        int kd = k / 9 - 1, kh = (k / 3) % 3 - 1, kw = k % 3 - 1;
        int pd = d + kd, ph = h + kh, pw = w + kw;
        bool valid = (pd >= 0) & (pd < D_) & (ph >= 0) & (ph < H_) & (pw >= 0) & (pw < W_);
        int pdc = min(max(pd, 0), D_ - 1);
        int phc = min(max(ph, 0), H_ - 1);
        int pwc = min(max(pw, 0), W_ - 1);
        int pix = (pdc * H_ + phc) * W_ + pwc;
        u32x4 pv[6];
#pragma unroll
        for (int cc = 0; cc < 6; ++cc) pv[cc] = plane[cc][pix];   // coalesced 16B
#pragma unroll
        for (int cc = 0; cc < 6; ++cc) {
            if (!valid) pv[cc] = z;
            *(u32x4*)&S[wid][lane][(cc ^ l7) * 8] = pv[cc];
        }
        const unsigned short* wk = wf + (size_t)k * 4096 + lane * 8;
        bf16x8 a[4][2];
#pragma unroll
        for (int mt = 0; mt < 4; ++mt)
#pragma unroll
            for (int ks = 0; ks < 2; ++ks)
                a[mt][ks] = *(const bf16x8*)&wk[(mt * 2 + ks) * 512];
#pragma unroll
        for (int nt = 0; nt < 4; ++nt) {
            const unsigned short* sr = &S[wid][nt * 16 + li][0];
            bf16x8 b0 = *(const bf16x8*)&sr[((0 + g) ^ l7) * 8];
            bf16x8 b1 = *(const bf16x8*)&sr[((4 + g) ^ l7) * 8];
#pragma unroll
            for (int mt = 0; mt < 4; ++mt) {
                acc[mt][nt] = __builtin_amdgcn_mfma_f32_16x16x32_bf16(a[mt][0], b0, acc[mt][nt], 0, 0, 0);
                acc[mt][nt] = __builtin_amdgcn_mfma_f32_16x16x32_bf16(a[mt][1], b1, acc[mt][nt], 0, 0, 0);
            }
        }
    }

    // cross-wave tap reduction through S (two 8KB phases, static indexing).
    // Barrier FIRST: wave 0 must be done reading its staging tile (XCH aliases
    // S[0]) before wave 1 overwrites it.
    float* XCH = (float*)&S[0][0][0];
    __syncthreads();
    if (wid == 1) {
#pragma unroll
        for (int mt = 0; mt < 2; ++mt)
#pragma unroll
            for (int nt = 0; nt < 4; ++nt)
                *(f32x4*)(XCH + (mt * 4 + nt) * 256 + lane * 4) = acc[mt][nt];
    }
    __syncthreads();
    if (wid == 0) {
#pragma unroll
        for (int mt = 0; mt < 2; ++mt)
#pragma unroll
            for (int nt = 0; nt < 4; ++nt)
                acc[mt][nt] += *(f32x4*)(XCH + (mt * 4 + nt) * 256 + lane * 4);
    }
    __syncthreads();
    if (wid == 1) {
#pragma unroll
        for (int mt = 2; mt < 4; ++mt)
#pragma unroll
            for (int nt = 0; nt < 4; ++nt)
                *(f32x4*)(XCH + ((mt - 2) * 4 + nt) * 256 + lane * 4) = acc[mt][nt];
    }
    __syncthreads();
    if (wid == 1) return;
#pragma unroll
    for (int mt = 2; mt < 4; ++mt)
#pragma unroll
        for (int nt = 0; nt < 4; ++nt)
            acc[mt][nt] += *(f32x4*)(XCH + ((mt - 2) * 4 + nt) * 256 + lane * 4);

    int s0 = base - b * DHW_;
#pragma unroll
    for (int mt = 0; mt < 4; ++mt) {
#pragma unroll
        for (int r = 0; r < 4; ++r) {
            int oc = mt * 16 + 4 * g + r;
            if (oc < OFFC_) {
                float bb = bo[oc];
#pragma unroll
                for (int nt = 0; nt < 4; ++nt) {
                    size_t addr = ((size_t)b * OFFC_ + oc) * DHW_ + (s0 + nt * 16 + li);
                    off[addr] = acc[mt][nt][r] + bb;
                }
            }
        }
    }
}

// ---------------- deformable conv (bilinear HW, integer D) via MFMA ----------------
template <int LEAKY, int RESID, int CLOUT>
__global__ void __launch_bounds__(128) deform_mfma(
    const unsigned short* __restrict__ scl,   // [6][NLOC][8] bf16 chunk-planes
    const float* __restrict__ off,            // [B][54][DHW] fp32
    const unsigned short* __restrict__ wf,    // frag-packed, MT=3
    const float* __restrict__ bias,           // [48]
    const float* __restrict__ resid,          // [B][48][DHW] fp32 (RESID)
    float* __restrict__ dstf,                 // [B][48][DHW] fp32 (!CLOUT)
    unsigned short* __restrict__ dstcl) {     // [6][NLOC][8] bf16 (CLOUT)
    __shared__ unsigned short S[2][64][64];
    int tid = threadIdx.x, wid = tid >> 6, lane = tid & 63;
    int base = xcd_swizzle(blockIdx.x, gridDim.x) * 64;
    int loc = base + lane;
    int b = loc / DHW_;
    int sp = loc - b * DHW_;
    int w = sp % W_; int t1 = sp / W_;
    int h = t1 % H_; int d = t1 / H_;
    int g = lane >> 4, li = lane & 15, l7 = lane & 7;

    u32x4 z = {0, 0, 0, 0};
    *(u32x4*)&S[wid][lane][(6 ^ l7) * 8] = z;
    *(u32x4*)&S[wid][lane][(7 ^ l7) * 8] = z;

    f32x4 acc[3][4];
#pragma unroll
    for (int mt = 0; mt < 3; ++mt)
#pragma unroll
        for (int nt = 0; nt < 4; ++nt) acc[mt][nt] = (f32x4){0.f, 0.f, 0.f, 0.f};

    const u32x4* plane[6];
#pragma unroll
    for (int q = 0; q < 6; ++q)
        plane[q] = (const u32x4*)(scl + ((size_t)q * NLOC_ + (size_t)b * DHW_) * 8);
    const float* ob = off + (size_t)b * (OFFC_ * DHW_) + sp;

#pragma unroll 1
    for (int i = 0; i < 14; ++i) {
        int k = wid + 2 * i;
        if (k >= 27) break;
        int kd = k / 9 - 1, kh = (k / 3) % 3 - 1, kw = k % 3 - 1;
        int pd = d + kd;
        bool vd = (pd >= 0) & (pd < D_);
        int pdc = min(max(pd, 0), D_ - 1);

        float odh = ob[(size_t)(2 * k + 0) * DHW_];
        float odw = ob[(size_t)(2 * k + 1) * DHW_];
        float phf = (float)(h + kh) + odh;
        float pwf = (float)(w + kw) + odw;
        float h0f = floorf(phf), w0f = floorf(pwf);
        float th = phf - h0f, tw = pwf - w0f;
        int h0 = (int)h0f, w0 = (int)w0f;

        int pix[4];
        f32x4 cw;
#pragma unroll
        for (int dh = 0; dh < 2; ++dh) {
            int hh = h0 + dh;
            bool vh = vd & (hh >= 0) & (hh < H_);
            int hhc = min(max(hh, 0), H_ - 1);
            float wh = dh ? th : 1.0f - th;
#pragma unroll
            for (int dw = 0; dw < 2; ++dw) {
                int ww = w0 + dw;
                bool v = vh & (ww >= 0) & (ww < W_);
                int wwc = min(max(ww, 0), W_ - 1);
                float wwt = dw ? tw : 1.0f - tw;
                pix[dh * 2 + dw] = (pdc * H_ + hhc) * W_ + wwc;   // clamped in-bounds
                cw[dh * 2 + dw] = v ? wh * wwt : 0.0f;
            }
        }
        f32x2 w0p = {cw[0], cw[0]}, w1p = {cw[1], cw[1]};
        f32x2 w2p = {cw[2], cw[2]}, w3p = {cw[3], cw[3]};

        // two halves of 12 staged 16B gathers (3 chunk-planes x 4 corners)
#pragma unroll
        for (int half = 0; half < 2; ++half) {
            u32x4 st[3][4];
#pragma unroll
            for (int cc = 0; cc < 3; ++cc)
#pragma unroll
                for (int j = 0; j < 4; ++j)
                    st[cc][j] = plane[half * 3 + cc][pix[j]];
#pragma unroll
            for (int cc = 0; cc < 3; ++cc) {
                u32x4 pv = interp4_pk(st[cc][0], st[cc][1], st[cc][2], st[cc][3],
                                      w0p, w1p, w2p, w3p);
                *(u32x4*)&S[wid][lane][((half * 3 + cc) ^ l7) * 8] = pv;
            }
        }

        const unsigned short* wk = wf + (size_t)k * 3072 + lane * 8;
        bf16x8 a[3][2];
#pragma unroll
        for (int mt = 0; mt < 3; ++mt)
#pragma unroll
            for (int ks = 0; ks < 2; ++ks)
                a[mt][ks] = *(const bf16x8*)&wk[(mt * 2 + ks) * 512];
#pragma unroll
        for (int nt = 0; nt < 4; ++nt) {
            const unsigned short* sr = &S[wid][nt * 16 + li][0];
            bf16x8 b0 = *(const bf16x8*)&sr[((0 + g) ^ l7) * 8];
            bf16x8 b1 = *(const bf16x8*)&sr[((4 + g) ^ l7) * 8];
#pragma unroll
            for (int mt = 0; mt < 3; ++mt) {
                acc[mt][nt] = __builtin_amdgcn_mfma_f32_16x16x32_bf16(a[mt][0], b0, acc[mt][nt], 0, 0, 0);
                acc[mt][nt] = __builtin_amdgcn_mfma_f32_16x16x32_bf16(a[mt][1], b1, acc[mt][nt], 0, 0, 0);
            }
        }
    }

    // cross-wave tap reduction through S[1] (keeps S[0] free for CLOUT
    // transpose). Barrier first: no wave may still be using its staging tile.
    float* XCH = (float*)&S[1][0][0];   // 8KB = 8 groups of 1KB
    __syncthreads();
    if (wid == 1) {
#pragma unroll
        for (int mt = 0; mt < 2; ++mt)
#pragma unroll
            for (int nt = 0; nt < 4; ++nt)
                *(f32x4*)(XCH + (mt * 4 + nt) * 256 + lane * 4) = acc[mt][nt];
    }
    __syncthreads();
    if (wid == 0) {
#pragma unroll
        for (int mt = 0; mt < 2; ++mt)
#pragma unroll
            for (int nt = 0; nt < 4; ++nt)
                acc[mt][nt] += *(f32x4*)(XCH + (mt * 4 + nt) * 256 + lane * 4);
    }
    __syncthreads();
    if (wid == 1) {
#pragma unroll
        for (int nt = 0; nt < 4; ++nt)
            *(f32x4*)(XCH + nt * 256 + lane * 4) = acc[2][nt];
    }
    __syncthreads();
    if (wid == 1) return;
#pragma unroll
    for (int nt = 0; nt < 4; ++nt)
        acc[2][nt] += *(f32x4*)(XCH + nt * 256 + lane * 4);

    if (CLOUT) {
        // Transpose D-tile through wave0's (now free) S[0] tile, then write
        // bf16 chunk-planes: 16B/lane dense per plane, fully coalesced.
        unsigned short* Sb = &S[0][0][0];   // row stride 64 u16 = 128 B
#pragma unroll
        for (int mt = 0; mt < 3; ++mt) {
#pragma unroll
            for (int nt = 0; nt < 4; ++nt) {
                float v[4];
#pragma unroll
                for (int r = 0; r < 4; ++r) {
                    int oc = mt * 16 + 4 * g + r;
                    float t = acc[mt][nt][r] + bias[oc];
                    if (LEAKY) t = (t >= 0.f) ? t : 0.1f * t;
                    v[r] = t;
                }
                int row = nt * 16 + li;
                int colb = (mt * 32 + 8 * g) ^ ((li & 7) << 4);
                u32x2 pp = {cvt_pk_bf16(v[0], v[1]), cvt_pk_bf16(v[2], v[3])};
                *(u32x2*)((char*)(Sb + (size_t)row * 64) + colb) = pp;
            }
        }
        unsigned short* myrow = Sb + (size_t)lane * 64;
#pragma unroll
        for (int s = 0; s < 6; ++s) {
            u32x4 c = *(u32x4*)((char*)myrow + ((s * 16) ^ ((lane & 7) << 4)));
            *(u32x4*)(dstcl + ((size_t)s * NLOC_ + loc) * 8) = c;
        }
    } else {
        int s0 = base - b * DHW_;
#pragma unroll
        for (int mt = 0; mt < 3; ++mt) {
#pragma unroll
            for (int r = 0; r < 4; ++r) {
                int oc = mt * 16 + 4 * g + r;
                float bb = bias[oc];
#pragma unroll
                for (int nt = 0; nt < 4; ++nt) {
                    size_t addr = ((size_t)b * C_ + oc) * DHW_ + (s0 + nt * 16 + li);
                    float v = acc[mt][nt][r] + bb;
                    if (LEAKY) v = (v >= 0.0f) ? v : 0.1f * v;
                    if (RESID) v += resid[addr];
                    dstf[addr] = v;
                }
            }
        }
    }
}

extern "C" void kernel_launch(void* const* d_in, const int* in_sizes, int n_in,
                              void* d_out, int out_size, void* d_ws, size_t ws_size,
                              hipStream_t stream) {
    const float* x      = (const float*)d_in[0];
    const float* w_off0 = (const float*)d_in[1];
    const float* b_off0 = (const float*)d_in[2];
    const float* w0     = (const float*)d_in[3];
    const float* b0     = (const float*)d_in[4];
    const float* w_off1 = (const float*)d_in[5];
    const float* b_off1 = (const float*)d_in[6];
    const float* w1     = (const float*)d_in[7];
    const float* b1     = (const float*)d_in[8];
    float* out = (float*)d_out;

    // ws: off (54*NLOC f32) | xcl (48*NLOC bf16) | hcl (48*NLOC bf16) | wf_off | wf_conv
    float* off_buf = (float*)d_ws;
    unsigned short* xcl = (unsigned short*)(off_buf + (size_t)OFFC_ * NLOC_);
    unsigned short* hcl = xcl + (size_t)NLOC_ * 48;
    unsigned short* wf_off  = hcl + (size_t)NLOC_ * 48;
    unsigned short* wf_conv = wf_off + 27 * 4 * 1024;

    dim3 blk128(128), blk256(256);
    int nblk = NLOC_ / 64;    // 2352 (divisible by 8)

    to_cl_kernel<<<NLOC_ / 256, blk256, 0, stream>>>(x, xcl);

    // --- layer 0 ---
    repack_frag_kernel<<<(27 * 4 * 1024 + 255) / 256, blk256, 0, stream>>>(w_off0, wf_off, OFFC_, 4);
    repack_frag_kernel<<<(27 * 3 * 1024 + 255) / 256, blk256, 0, stream>>>(w0, wf_conv, C_, 3);
    offconv_mfma<<<nblk, blk128, 0, stream>>>(xcl, wf_off, b_off0, off_buf);
    deform_mfma<1, 0, 1><<<nblk, blk128, 0, stream>>>(xcl, off_buf, wf_conv, b0, nullptr, nullptr, hcl);

    // --- layer 1 ---
    repack_frag_kernel<<<(27 * 4 * 1024 + 255) / 256, blk256, 0, stream>>>(w_off1, wf_off, OFFC_, 4);
    repack_frag_kernel<<<(27 * 3 * 1024 + 255) / 256, blk256, 0, stream>>>(w1, wf_conv, C_, 3);
    offconv_mfma<<<nblk, blk128, 0, stream>>>(hcl, wf_off, b_off1, off_buf);
    deform_mfma<0, 1, 0><<<nblk, blk128, 0, stream>>>(hcl, off_buf, wf_conv, b1, x, out, nullptr);
}